// Round 4
// baseline (261.306 us; speedup 1.0000x reference)
//
#include <hip/hip_runtime.h>
#include <math.h>
#include <float.h>

// Problem constants (fixed by the reference)
#define Bn   64
#define Sn   512
#define FWn  6
#define Wn   507     // S - FW + 1
#define WT   32      // windows per block (2 sub-tiles of 16)
#define NTILE 16     // 507 windows -> 16 tiles of 32

#define LOG2E  1.4426950408889634f
#define LOG2E2 2.8853900817779268f

typedef __attribute__((ext_vector_type(8))) _Float16 half8;
typedef __attribute__((ext_vector_type(4))) _Float16 half4;
typedef __attribute__((ext_vector_type(2))) _Float16 half2t;
typedef __attribute__((ext_vector_type(4))) float f32x4;

// Folded activations (weights pre-scaled by log2e / 2log2e in pack_w):
//   sig(y)   = rcp(1 + exp2(-y))          [y = x*log2e]
//   tanhg(y) = 1 - 2*rcp(exp2(y) + 1)     [y = 2x*log2e]
//   tanhc(c) = 1 - 2*rcp(exp2(c*2log2e)+1)  [c in true units]
__device__ __forceinline__ float sigf(float y) {
    return __builtin_amdgcn_rcpf(1.0f + __builtin_amdgcn_exp2f(-y));
}
__device__ __forceinline__ float tanhg(float y) {
    return 1.0f - 2.0f * __builtin_amdgcn_rcpf(__builtin_amdgcn_exp2f(y) + 1.0f);
}
__device__ __forceinline__ float tanhc(float c) {
    return 1.0f - 2.0f * __builtin_amdgcn_rcpf(__builtin_amdgcn_exp2f(c * LOG2E2) + 1.0f);
}

// ---------------------------------------------------------------------------
// Kernel 0: pack w_ih and w_hh into fp16 B-fragment order for
// mfma_f32_16x16x32_f16, PRE-SCALED by log2e (gates i,f,o) / 2log2e (gate g)
// so activations use raw v_exp_f32 (exp2) with no per-element scaling mul.
//   pack[((nt*4 + ks)*64 + lane)*8 + j] = s_g * w[nt*16 + (lane&15)][ks*32 + (lane>>4)*8 + j]
// Row-tile nt = g*8 + ut. 65536 elements each.
// ---------------------------------------------------------------------------
__global__ void __launch_bounds__(256)
pack_w_kernel(const float* __restrict__ w_ih, const float* __restrict__ w_hh,
              _Float16* __restrict__ wih_p, _Float16* __restrict__ whh_p)
{
    const int idx = blockIdx.x * 256 + threadIdx.x;      // 0..65535
    const int j  = idx & 7;
    const int L  = (idx >> 3) & 63;
    const int ks = (idx >> 9) & 3;
    const int nt = idx >> 11;
    const int row = nt * 16 + (L & 15);
    const int col = ks * 32 + (L >> 4) * 8 + j;
    const float sc = ((nt >> 3) == 2) ? LOG2E2 : LOG2E;   // gate g doubled
    wih_p[idx] = (_Float16)(sc * w_ih[row * 128 + col]);
    whh_p[idx] = (_Float16)(sc * w_hh[row * 128 + col]);
}

// ---------------------------------------------------------------------------
// Kernel 1 (fused MFMA LSTM), 32 windows (2 sub-tiles of 16) per 512-thread
// block; wave ut owns unit-tile ut for both sub-tiles.
//   R13 analysis: kernel is VALU-ISSUE-bound (VALUBusy 50% + Mfma 17% at only
//   ~11 waves/CU avg). Two levers applied:
//   1. P (x-projection) kept in REGISTERS, not LDS. Pt was wave-private in
//      columns (wave ut reads only cols [ut*64,ut*64+64)); the per-step +st
//      row shift is lane-local when (st+r)<=3, else a uniform q-rotation:
//      1 ds_bpermute (rot 16/32 lanes) + 1 cndmask (source q==0 / q<2 picks
//      px[s+1] vs px[s]). Only 14/48 (st,sub,r) slots cross. Removes 96
//      ds_read_b64 + all Pt stores + the phase1->2 barrier; LDS 54272->16384
//      -> occupancy cap rises to the 32-wave/CU wave limit.
//   2. exp2 weight folding (see pack_w): -4 VALU per row-element.
//   whf: source declares the array; at budget 128 the allocator chooses
//   residency vs streaming (R12: streamed at 64 — both acceptable).
// grid 64*16, block 512.
// ---------------------------------------------------------------------------
__global__ void __launch_bounds__(512, 4)
lstm_kernel(const int* __restrict__ inputs, const float* __restrict__ embed,
            const _Float16* __restrict__ wih_p, const _Float16* __restrict__ whh_p,
            const float* __restrict__ b_ih, const float* __restrict__ b_hh,
            float* __restrict__ partial)
{
    __shared__ __align__(16) _Float16 hsA[2][2][2048];      // 16 KiB total LDS
    const int t    = threadIdx.x;
    const int L    = t & 63;
    const int ut   = t >> 6;          // wave index = unit-tile 0..7
    const int b    = blockIdx.x >> 4;
    const int tile = blockIdx.x & 15;
    const int w0   = tile * WT;
    const int q  = L >> 4;
    const int ln = L & 15;
    const int j8 = L & 7;
    const int u  = ut * 16 + ln;      // this lane's hidden unit (B n-index)

    // register-resident P: px{A,B}[mt][pr] = packed fp16 gate pairs (0,1)/(2,3)
    // for projection row mt*16 + q*4 + pr at unit u. 24 VGPRs.
    unsigned pxA[3][4], pxB[3][4];

    // ---- phase 1: x-proj (3 m-tiles = rows 0..47; rows >42 garbage, unread) ----
    {
        f32x4 accx[3][4];   // [mt][gate], init with folded bias
#pragma unroll
        for (int g = 0; g < 4; ++g) {
            const float sc = (g == 2) ? LOG2E2 : LOG2E;
            const float bg = sc * (b_ih[g * 128 + u] + b_hh[g * 128 + u]);
            accx[0][g] = (f32x4){bg, bg, bg, bg};
            accx[1][g] = accx[0][g];
            accx[2][g] = accx[0][g];
        }
        int tok[3];
#pragma unroll
        for (int mt = 0; mt < 3; ++mt) {
            int s = w0 + mt * 16 + ln; s = s < 511 ? s : 511;  // clamp (masked at max)
            tok[mt] = inputs[b * Sn + s];
        }
#pragma unroll
        for (int ks = 0; ks < 4; ++ks) {
            half8 ax[3];
#pragma unroll
            for (int mt = 0; mt < 3; ++mt) {
                const float* er = embed + (size_t)tok[mt] * 128 + ks * 32 + q * 8;
                float4 e0 = *(const float4*)er;
                float4 e1 = *(const float4*)(er + 4);
                half8 a;
                a[0] = (_Float16)e0.x; a[1] = (_Float16)e0.y;
                a[2] = (_Float16)e0.z; a[3] = (_Float16)e0.w;
                a[4] = (_Float16)e1.x; a[5] = (_Float16)e1.y;
                a[6] = (_Float16)e1.z; a[7] = (_Float16)e1.w;
                ax[mt] = a;
            }
#pragma unroll
            for (int g = 0; g < 4; ++g) {
                half8 bw = *(const half8*)(wih_p + ((size_t)((g * 8 + ut) * 4 + ks) * 64 + L) * 8);
#pragma unroll
                for (int mt = 0; mt < 3; ++mt)
                    accx[mt][g] = __builtin_amdgcn_mfma_f32_16x16x32_f16(ax[mt], bw, accx[mt][g], 0, 0, 0);
            }
        }
        // pack to register px (this lane holds quad-row mt*4+q, pr=r)
#pragma unroll
        for (int mt = 0; mt < 3; ++mt)
#pragma unroll
            for (int r = 0; r < 4; ++r) {
                pxA[mt][r] = __builtin_bit_cast(unsigned,
                    (half2t){(_Float16)accx[mt][0][r], (_Float16)accx[mt][1][r]});
                pxB[mt][r] = __builtin_bit_cast(unsigned,
                    (half2t){(_Float16)accx[mt][2][r], (_Float16)accx[mt][3][r]});
            }
    }

    // w_hh B-fragments for this wave's unit-tile (allocator decides residency)
    half8 whf[4][4];    // [gate][ks]
#pragma unroll
    for (int g = 0; g < 4; ++g)
#pragma unroll
        for (int ks = 0; ks < 4; ++ks)
            whf[g][ks] = *(const half8*)(whh_p + ((size_t)((g * 8 + ut) * 4 + ks) * 64 + L) * 8);

    // shuffle helpers for the P q-rotation
    const int rot16 = ((L + 16) & 63) << 2;     // ds_bpermute byte index
    const int rot32 = ((L + 32) & 63) << 2;
    const bool q0   = (q == 0);
    const bool qlt2 = (q < 2);

    // h scatter address components (A-fragment layout for unit u, window m)
    const int ks_h = ut >> 1;
    const int qp   = (ut & 1) * 2 + (ln >> 3);

    float cst[2][4] = {{0.f, 0.f, 0.f, 0.f}, {0.f, 0.f, 0.f, 0.f}};
    float mv = -FLT_MAX;

    // ---- steps 0..5, two sub-tiles per barrier interval; 1 barrier/step ----
#pragma unroll
    for (int st = 0; st < FWn; ++st) {
        if (st > 0) __syncthreads();        // prev step's h scatter visible
#pragma unroll
        for (int sub = 0; sub < 2; ++sub) {
            f32x4 acc[4];                   // [gate] over r
#pragma unroll
            for (int r = 0; r < 4; ++r) {
                const int k = st + r;       // P row shift (compile-time)
                unsigned lo, hi;
                if (k <= 3) {               // lane-local
                    lo = pxA[sub][k]; hi = pxB[sub][k];
                } else if (k <= 7) {        // quad+1: rotate q by 1
                    unsigned sa = q0 ? pxA[sub + 1][k - 4] : pxA[sub][k - 4];
                    unsigned sb = q0 ? pxB[sub + 1][k - 4] : pxB[sub][k - 4];
                    lo = (unsigned)__builtin_amdgcn_ds_bpermute(rot16, (int)sa);
                    hi = (unsigned)__builtin_amdgcn_ds_bpermute(rot16, (int)sb);
                } else {                    // k == 8: rotate q by 2
                    unsigned sa = qlt2 ? pxA[sub + 1][0] : pxA[sub][0];
                    unsigned sb = qlt2 ? pxB[sub + 1][0] : pxB[sub][0];
                    lo = (unsigned)__builtin_amdgcn_ds_bpermute(rot32, (int)sa);
                    hi = (unsigned)__builtin_amdgcn_ds_bpermute(rot32, (int)sb);
                }
                half2t l2 = __builtin_bit_cast(half2t, lo);
                half2t h2 = __builtin_bit_cast(half2t, hi);
                acc[0][r] = (float)l2[0]; acc[1][r] = (float)l2[1];
                acc[2][r] = (float)h2[0]; acc[3][r] = (float)h2[1];
            }
            if (st > 0) {
                const _Float16* hb = hsA[(st + 1) & 1][sub];   // h(st-1)
#pragma unroll
                for (int ks = 0; ks < 4; ++ks) {
                    half8 ah = *(const half8*)(hb + (ks * 64 + L) * 8);
#pragma unroll
                    for (int g = 0; g < 4; ++g)
                        acc[g] = __builtin_amdgcn_mfma_f32_16x16x32_f16(ah, whf[g][ks], acc[g], 0, 0, 0);
                }
            }
            _Float16* buf = hsA[st & 1][sub];
#pragma unroll
            for (int r = 0; r < 4; ++r) {
                float ii = sigf(acc[0][r]);
                float ff = sigf(acc[1][r]);
                float gg = tanhg(acc[2][r]);
                float oo = sigf(acc[3][r]);
                float cc = ff * cst[sub][r] + ii * gg;
                cst[sub][r] = cc;
                float hv = oo * tanhc(cc);
                if (st < FWn - 1) {
                    buf[ks_h * 512 + (qp * 16 + q * 4 + r) * 8 + j8] = (_Float16)hv;
                } else {
                    const int w = w0 + sub * 16 + q * 4 + r;
                    mv = fmaxf(mv, (w < Wn) ? hv : -FLT_MAX);
                }
            }
        }
    }

    // ---- reduce max across q; lanes q==0 hold result for unit u ----
    mv = fmaxf(mv, __shfl_xor(mv, 16));
    mv = fmaxf(mv, __shfl_xor(mv, 32));
    if (q == 0)
        partial[(size_t)(b * NTILE + tile) * 128 + u] = mv;
}

// ---------------------------------------------------------------------------
// Kernel 2: feat[b][u] = max over tiles; out[b][c] = feat . fc_w[c] + fc_b[c]
// grid 64, block 128
// ---------------------------------------------------------------------------
__global__ void __launch_bounds__(128)
final_kernel(const float* __restrict__ partial, const float* __restrict__ fc_w,
             const float* __restrict__ fc_b, float* __restrict__ out)
{
    const int b = blockIdx.x;
    const int u = threadIdx.x;
    float m = -FLT_MAX;
#pragma unroll
    for (int tl = 0; tl < NTILE; ++tl)
        m = fmaxf(m, partial[(size_t)(b * NTILE + tl) * 128 + u]);
    float v0 = m * fc_w[u];
    float v1 = m * fc_w[128 + u];
#pragma unroll
    for (int off = 1; off < 64; off <<= 1) {
        v0 += __shfl_xor(v0, off);
        v1 += __shfl_xor(v1, off);
    }
    __shared__ float red[2][2];
    if ((u & 63) == 0) { red[u >> 6][0] = v0; red[u >> 6][1] = v1; }
    __syncthreads();
    if (u == 0) {
        out[b * 2 + 0] = red[0][0] + red[1][0] + fc_b[0];
        out[b * 2 + 1] = red[0][1] + red[1][1] + fc_b[1];
    }
}

// ---------------------------------------------------------------------------
extern "C" void kernel_launch(void* const* d_in, const int* in_sizes, int n_in,
                              void* d_out, int out_size, void* d_ws, size_t ws_size,
                              hipStream_t stream)
{
    const int*   inputs = (const int*)d_in[0];
    // d_in[1] = lengths : unused by the reference
    const float* embed  = (const float*)d_in[2];
    const float* w_ih   = (const float*)d_in[3];
    const float* w_hh   = (const float*)d_in[4];
    const float* b_ih   = (const float*)d_in[5];
    const float* b_hh   = (const float*)d_in[6];
    const float* fc_w   = (const float*)d_in[7];
    const float* fc_b   = (const float*)d_in[8];
    float* out = (float*)d_out;

    // workspace: partial (512 KiB) | wih_p, whh_p (128 KiB each)
    float*    partial = (float*)d_ws;
    _Float16* wih_p   = (_Float16*)(partial + Bn * NTILE * 128);
    _Float16* whh_p   = wih_p + 65536;

    pack_w_kernel<<<dim3(256), 256, 0, stream>>>(w_ih, w_hh, wih_p, whh_p);
    lstm_kernel<<<dim3(Bn * NTILE), 512, 0, stream>>>(inputs, embed, wih_p, whh_p,
                                                      b_ih, b_hh, partial);
    final_kernel<<<dim3(Bn), 128, 0, stream>>>(partial, fc_w, fc_b, out);
}

// Round 5
// 141.445 us; speedup vs baseline: 1.8474x; 1.8474x over previous
//
#include <hip/hip_runtime.h>
#include <math.h>
#include <float.h>

// Problem constants (fixed by the reference)
#define Bn   64
#define Sn   512
#define FWn  6
#define Wn   507     // S - FW + 1
#define WT   16      // windows per block (R14: one sub-tile; balanced gens)
#define NTILE 32     // 507 windows -> 32 tiles of 16

#define PROWS   21    // projection rows per block (16 windows + FW-1)
#define PSTRIDE 512   // fp16 elems per Pt row (1024 B); phase-conflict-free (R10)

#define LOG2E  1.4426950408889634f
#define LOG2E2 2.8853900817779268f

typedef __attribute__((ext_vector_type(8))) _Float16 half8;
typedef __attribute__((ext_vector_type(4))) _Float16 half4;
typedef __attribute__((ext_vector_type(4))) float f32x4;

// ---------------------------------------------------------------------------
// Kernel 0: pack w_ih and w_hh into fp16 B-fragment order for
// mfma_f32_16x16x32_f16, PRE-SCALED by log2e (gates i,f,o) / 2log2e (gate g)
// so activations use raw v_exp_f32 (exp2) with no range-conversion muls.
//   pack[((nt*4+ks)*64+lane)*8+j] = sc * w[nt*16+(lane&15)][ks*32+(lane>>4)*8+j]
// Row-tile nt = g*8 + ut. 65536 elements each.
// ---------------------------------------------------------------------------
__global__ void __launch_bounds__(256)
pack_w_kernel(const float* __restrict__ w_ih, const float* __restrict__ w_hh,
              _Float16* __restrict__ wih_p, _Float16* __restrict__ whh_p)
{
    const int idx = blockIdx.x * 256 + threadIdx.x;      // 0..65535
    const int j  = idx & 7;
    const int L  = (idx >> 3) & 63;
    const int ks = (idx >> 9) & 3;
    const int nt = idx >> 11;
    const int row = nt * 16 + (L & 15);
    const int col = ks * 32 + (L >> 4) * 8 + j;
    const float sc = ((nt >> 3) == 2) ? LOG2E2 : LOG2E;   // gate g doubled
    wih_p[idx] = (_Float16)(sc * w_ih[row * 128 + col]);
    whh_p[idx] = (_Float16)(sc * w_hh[row * 128 + col]);
}

// ---------------------------------------------------------------------------
// Kernel 1 (fused MFMA LSTM), 16 windows per 512-thread block (8 waves; wave
// ut owns unit-tile ut = units [ut*16, ut*16+16)).
//   R13 post-mortem: allocator pins 64 VGPRs on this kernel regardless of
//   launch bounds (R12+R13 evidence); register-P + register-whf (~127 live)
//   spilled to scratch (330 MB writes/dispatch). R14 reverts to the trusted
//   R12 structure (Pt in LDS, whf streamed from L2) and fixes the two
//   counter-quantified costs:
//   1. GENERATION BALANCE: R12's 1024 blocks at 3-blocks/CU residency ran
//      gens of 3 + 1 (avg occupancy 35%). Now: 2048 blocks, LDS 29696 B,
//      single sub-tile -> 4 blocks/CU (wave-capped) = 2 BALANCED gens of 4.
//   2. TRANS-PIPE CUT: fused gate algebra sig(i)*tanh(g) = (1-b)/((1+a)(1+b)),
//      sig(o)*tanh(c) = (1-d)/((1+co)(1+d)): 5 exp2 + 3 rcp per element
//      (was 5+5), plus exp2 weight folding removes 4 range-conversion muls.
//      Overflow-safe: worst-case |pre-activation args| < 50 << 128.
//   Register pressure in the step loop (~45 peak) fits the 64-VGPR pin.
// grid 64*32, block 512.
// ---------------------------------------------------------------------------
__global__ void __launch_bounds__(512, 4)
lstm_kernel(const int* __restrict__ inputs, const float* __restrict__ embed,
            const _Float16* __restrict__ wih_p, const _Float16* __restrict__ whh_p,
            const float* __restrict__ b_ih, const float* __restrict__ b_hh,
            float* __restrict__ partial)
{
    __shared__ __align__(16) _Float16 Pt[PROWS * PSTRIDE];  // 21 KiB
    __shared__ __align__(16) _Float16 hsA[2][2048];         // 8 KiB
    const int t    = threadIdx.x;
    const int L    = t & 63;
    const int ut   = t >> 6;          // wave index = unit-tile 0..7
    const int b    = blockIdx.x >> 5;
    const int tile = blockIdx.x & 31;
    const int w0   = tile * WT;
    const int q  = L >> 4;
    const int ln = L & 15;
    const int j8 = L & 7;
    const int u  = ut * 16 + ln;      // this lane's hidden unit (B n-index)

    // ---- phase 1: x-proj (2 m-tiles = rows 0..31, stores clamped to 21) ----
    {
        f32x4 accx[2][4];   // [mt][gate], init with folded bias
#pragma unroll
        for (int g = 0; g < 4; ++g) {
            const float sc = (g == 2) ? LOG2E2 : LOG2E;
            const float bg = sc * (b_ih[g * 128 + u] + b_hh[g * 128 + u]);
            accx[0][g] = (f32x4){bg, bg, bg, bg};
            accx[1][g] = accx[0][g];
        }
        int tok[2];
#pragma unroll
        for (int mt = 0; mt < 2; ++mt) {
            int s = w0 + mt * 16 + ln; s = s < 511 ? s : 511;  // clamp (masked at max)
            tok[mt] = inputs[b * Sn + s];
        }
#pragma unroll
        for (int ks = 0; ks < 4; ++ks) {
            half8 ax[2];
#pragma unroll
            for (int mt = 0; mt < 2; ++mt) {
                const float* er = embed + (size_t)tok[mt] * 128 + ks * 32 + q * 8;
                float4 e0 = *(const float4*)er;
                float4 e1 = *(const float4*)(er + 4);
                half8 a;
                a[0] = (_Float16)e0.x; a[1] = (_Float16)e0.y;
                a[2] = (_Float16)e0.z; a[3] = (_Float16)e0.w;
                a[4] = (_Float16)e1.x; a[5] = (_Float16)e1.y;
                a[6] = (_Float16)e1.z; a[7] = (_Float16)e1.w;
                ax[mt] = a;
            }
#pragma unroll
            for (int g = 0; g < 4; ++g) {
                half8 bw = *(const half8*)(wih_p + ((size_t)((g * 8 + ut) * 4 + ks) * 64 + L) * 8);
#pragma unroll
                for (int mt = 0; mt < 2; ++mt)
                    accx[mt][g] = __builtin_amdgcn_mfma_f32_16x16x32_f16(ax[mt], bw, accx[mt][g], 0, 0, 0);
            }
        }
        // store gate-interleaved fp16 Pt rows (predicated to 21 rows)
#pragma unroll
        for (int mt = 0; mt < 2; ++mt)
#pragma unroll
            for (int r = 0; r < 4; ++r) {
                const int sl = mt * 16 + q * 4 + r;
                if (sl < PROWS) {
                    half4 o;
                    o[0] = (_Float16)accx[mt][0][r];
                    o[1] = (_Float16)accx[mt][1][r];
                    o[2] = (_Float16)accx[mt][2][r];
                    o[3] = (_Float16)accx[mt][3][r];
                    *(half4*)&Pt[sl * PSTRIDE + u * 4] = o;
                }
            }
    }

    // w_hh B-fragments, source-hoisted (R12 form: allocator streams from L2
    // at its 64-VGPR pin; this placement benched fastest).
    half8 whf[4][4];    // [gate][ks]
#pragma unroll
    for (int g = 0; g < 4; ++g)
#pragma unroll
        for (int ks = 0; ks < 4; ++ks)
            whf[g][ks] = *(const half8*)(whh_p + ((size_t)((g * 8 + ut) * 4 + ks) * 64 + L) * 8);

    __syncthreads();    // Pt visible to all waves

    // h scatter address components (A-fragment layout for unit u, window m)
    const int ks_h = ut >> 1;
    const int qp   = (ut & 1) * 2 + (ln >> 3);

    float cst[4] = {0.f, 0.f, 0.f, 0.f};
    float mv = -FLT_MAX;

    // ---- steps 0..5; 1 barrier/step ----
    for (int st = 0; st < FWn; ++st) {
        if (st > 0) __syncthreads();        // prev step's h scatter visible
        f32x4 acc[4];                       // [gate] over r
#pragma unroll
        for (int r = 0; r < 4; ++r) {
            half4 pv = *(const half4*)&Pt[(q * 4 + r + st) * PSTRIDE + u * 4];
            acc[0][r] = (float)pv[0]; acc[1][r] = (float)pv[1];
            acc[2][r] = (float)pv[2]; acc[3][r] = (float)pv[3];
        }
        if (st > 0) {
            const _Float16* hb = hsA[(st + 1) & 1];   // h(st-1)
#pragma unroll
            for (int ks = 0; ks < 4; ++ks) {
                half8 ah = *(const half8*)(hb + (ks * 64 + L) * 8);
#pragma unroll
                for (int g = 0; g < 4; ++g)
                    acc[g] = __builtin_amdgcn_mfma_f32_16x16x32_f16(ah, whf[g][ks], acc[g], 0, 0, 0);
            }
        }
        _Float16* buf = hsA[st & 1];
#pragma unroll
        for (int r = 0; r < 4; ++r) {
            // pre-activations already scaled: i',f',o' by log2e; g'' by 2log2e
            float a  = __builtin_amdgcn_exp2f(-acc[0][r]);   // exp(-i)
            float cf = __builtin_amdgcn_exp2f(-acc[1][r]);   // exp(-f)
            float bb = __builtin_amdgcn_exp2f(-acc[2][r]);   // exp(-2g)
            float co = __builtin_amdgcn_exp2f(-acc[3][r]);   // exp(-o)
            float ft  = __builtin_amdgcn_rcpf(1.0f + cf);                    // sig(f)
            float itg = (1.0f - bb) * __builtin_amdgcn_rcpf((1.0f + a) * (1.0f + bb)); // sig(i)*tanh(g)
            float cc  = fmaf(cst[r], ft, itg);
            cst[r] = cc;
            float d  = __builtin_amdgcn_exp2f(-LOG2E2 * cc);                 // exp(-2c)
            float hv = (1.0f - d) * __builtin_amdgcn_rcpf((1.0f + co) * (1.0f + d));   // sig(o)*tanh(c)
            if (st < FWn - 1) {
                buf[ks_h * 512 + (qp * 16 + q * 4 + r) * 8 + j8] = (_Float16)hv;
            } else {
                const int w = w0 + q * 4 + r;
                mv = fmaxf(mv, (w < Wn) ? hv : -FLT_MAX);
            }
        }
    }

    // ---- reduce max across q; lanes q==0 hold result for unit u ----
    mv = fmaxf(mv, __shfl_xor(mv, 16));
    mv = fmaxf(mv, __shfl_xor(mv, 32));
    if (q == 0)
        partial[(size_t)(b * NTILE + tile) * 128 + u] = mv;
}

// ---------------------------------------------------------------------------
// Kernel 2: feat[b][u] = max over tiles; out[b][c] = feat . fc_w[c] + fc_b[c]
// grid 64, block 128
// ---------------------------------------------------------------------------
__global__ void __launch_bounds__(128)
final_kernel(const float* __restrict__ partial, const float* __restrict__ fc_w,
             const float* __restrict__ fc_b, float* __restrict__ out)
{
    const int b = blockIdx.x;
    const int u = threadIdx.x;
    float m = -FLT_MAX;
#pragma unroll
    for (int tl = 0; tl < NTILE; ++tl)
        m = fmaxf(m, partial[(size_t)(b * NTILE + tl) * 128 + u]);
    float v0 = m * fc_w[u];
    float v1 = m * fc_w[128 + u];
#pragma unroll
    for (int off = 1; off < 64; off <<= 1) {
        v0 += __shfl_xor(v0, off);
        v1 += __shfl_xor(v1, off);
    }
    __shared__ float red[2][2];
    if ((u & 63) == 0) { red[u >> 6][0] = v0; red[u >> 6][1] = v1; }
    __syncthreads();
    if (u == 0) {
        out[b * 2 + 0] = red[0][0] + red[1][0] + fc_b[0];
        out[b * 2 + 1] = red[0][1] + red[1][1] + fc_b[1];
    }
}

// ---------------------------------------------------------------------------
extern "C" void kernel_launch(void* const* d_in, const int* in_sizes, int n_in,
                              void* d_out, int out_size, void* d_ws, size_t ws_size,
                              hipStream_t stream)
{
    const int*   inputs = (const int*)d_in[0];
    // d_in[1] = lengths : unused by the reference
    const float* embed  = (const float*)d_in[2];
    const float* w_ih   = (const float*)d_in[3];
    const float* w_hh   = (const float*)d_in[4];
    const float* b_ih   = (const float*)d_in[5];
    const float* b_hh   = (const float*)d_in[6];
    const float* fc_w   = (const float*)d_in[7];
    const float* fc_b   = (const float*)d_in[8];
    float* out = (float*)d_out;

    // workspace: partial (1 MiB) | wih_p, whh_p (128 KiB each)
    float*    partial = (float*)d_ws;
    _Float16* wih_p   = (_Float16*)(partial + Bn * NTILE * 128);
    _Float16* whh_p   = wih_p + 65536;

    pack_w_kernel<<<dim3(256), 256, 0, stream>>>(w_ih, w_hh, wih_p, whh_p);
    lstm_kernel<<<dim3(Bn * NTILE), 512, 0, stream>>>(inputs, embed, wih_p, whh_p,
                                                      b_ih, b_hh, partial);
    final_kernel<<<dim3(Bn), 128, 0, stream>>>(partial, fc_w, fc_b, out);
}

// Round 6
// 135.922 us; speedup vs baseline: 1.9225x; 1.0406x over previous
//
#include <hip/hip_runtime.h>
#include <math.h>
#include <float.h>

// Problem constants (fixed by the reference)
#define Bn   64
#define Sn   512
#define FWn  6
#define Wn   507     // S - FW + 1
#define WT   32      // windows per block (2 sub-tiles of 16) — R12 geometry
#define NTILE 16     // 507 windows -> 16 tiles of 32

#define PROWS   37    // projection rows per block (32 windows + FW-1)
#define PSTRIDE 512   // fp16 elems per Pt row (1024 B); phase-conflict-free (R10)

#define LOG2E  1.4426950408889634f
#define LOG2E2 2.8853900817779268f

typedef __attribute__((ext_vector_type(8))) _Float16 half8;
typedef __attribute__((ext_vector_type(4))) _Float16 half4;
typedef __attribute__((ext_vector_type(4))) float f32x4;

// ---------------------------------------------------------------------------
// Kernel 0: pack w_ih and w_hh into fp16 B-fragment order for
// mfma_f32_16x16x32_f16, PRE-SCALED by log2e (gates i,f,o) / 2log2e (gate g)
// so activations use raw v_exp_f32 (exp2) with no range-conversion muls.
//   pack[((nt*4+ks)*64+lane)*8+j] = sc * w[nt*16+(lane&15)][ks*32+(lane>>4)*8+j]
// Row-tile nt = g*8 + ut. 65536 elements each.
// ---------------------------------------------------------------------------
__global__ void __launch_bounds__(256)
pack_w_kernel(const float* __restrict__ w_ih, const float* __restrict__ w_hh,
              _Float16* __restrict__ wih_p, _Float16* __restrict__ whh_p)
{
    const int idx = blockIdx.x * 256 + threadIdx.x;      // 0..65535
    const int j  = idx & 7;
    const int L  = (idx >> 3) & 63;
    const int ks = (idx >> 9) & 3;
    const int nt = idx >> 11;
    const int row = nt * 16 + (L & 15);
    const int col = ks * 32 + (L >> 4) * 8 + j;
    const float sc = ((nt >> 3) == 2) ? LOG2E2 : LOG2E;   // gate g doubled
    wih_p[idx] = (_Float16)(sc * w_ih[row * 128 + col]);
    whh_p[idx] = (_Float16)(sc * w_hh[row * 128 + col]);
}

// ---------------------------------------------------------------------------
// Kernel 1 (fused MFMA LSTM), 32 windows (2 sub-tiles) per 512-thread block.
//   R15 diagnosis: kernel pinned at 64-66 µs across R12/R14 configs; the
//   invariant cost is per-step w_hh streaming from L2 (16 KiB/wave/step on
//   the barrier-serialized path). Root cause: __launch_bounds__ 2nd arg only
//   sets MIN waves/EU — the backend still targets 8 waves/EU (64 VGPRs) and
//   rematerializes whf in-loop (VGPR 64/64/60 in R12/R13/R14).
//   Fix: amdgpu_waves_per_eu(4,4) caps MAX waves/EU=4 -> allocator budget
//   128 VGPRs -> whf[4][4] (64 VGPRs) genuinely resident; step loop has
//   ZERO global loads. Occupancy capacity 16 waves/CU — proven non-binding
//   (R11: more occupancy, slower; R14: balanced gens, neutral).
//   Expected VGPR ~96-112; if WRITE_SIZE jumps it spilled (back off to
//   half-resident whf next).
// grid 64*16, block 512.
// ---------------------------------------------------------------------------
__global__ void __launch_bounds__(512)
__attribute__((amdgpu_waves_per_eu(4, 4)))
lstm_kernel(const int* __restrict__ inputs, const float* __restrict__ embed,
            const _Float16* __restrict__ wih_p, const _Float16* __restrict__ whh_p,
            const float* __restrict__ b_ih, const float* __restrict__ b_hh,
            float* __restrict__ partial)
{
    __shared__ __align__(16) _Float16 Pt[PROWS * PSTRIDE];  // 37 KiB
    __shared__ __align__(16) _Float16 hsA[2][2][2048];      // 16 KiB
    const int t    = threadIdx.x;
    const int L    = t & 63;
    const int ut   = t >> 6;          // wave index = unit-tile 0..7
    const int b    = blockIdx.x >> 4;
    const int tile = blockIdx.x & 15;
    const int w0   = tile * WT;
    const int q  = L >> 4;
    const int ln = L & 15;
    const int j8 = L & 7;
    const int u  = ut * 16 + ln;      // this lane's hidden unit (B n-index)

    // ---- phase 1: x-proj (3 m-tiles = rows 0..47, stores clamped to 37) ----
    {
        f32x4 accx[3][4];   // [mt][gate], init with folded bias
#pragma unroll
        for (int g = 0; g < 4; ++g) {
            const float sc = (g == 2) ? LOG2E2 : LOG2E;
            const float bg = sc * (b_ih[g * 128 + u] + b_hh[g * 128 + u]);
            accx[0][g] = (f32x4){bg, bg, bg, bg};
            accx[1][g] = accx[0][g];
            accx[2][g] = accx[0][g];
        }
        int tok[3];
#pragma unroll
        for (int mt = 0; mt < 3; ++mt) {
            int s = w0 + mt * 16 + ln; s = s < 511 ? s : 511;  // clamp (masked at max)
            tok[mt] = inputs[b * Sn + s];
        }
#pragma unroll
        for (int ks = 0; ks < 4; ++ks) {
            half8 ax[3];
#pragma unroll
            for (int mt = 0; mt < 3; ++mt) {
                const float* er = embed + (size_t)tok[mt] * 128 + ks * 32 + q * 8;
                float4 e0 = *(const float4*)er;
                float4 e1 = *(const float4*)(er + 4);
                half8 a;
                a[0] = (_Float16)e0.x; a[1] = (_Float16)e0.y;
                a[2] = (_Float16)e0.z; a[3] = (_Float16)e0.w;
                a[4] = (_Float16)e1.x; a[5] = (_Float16)e1.y;
                a[6] = (_Float16)e1.z; a[7] = (_Float16)e1.w;
                ax[mt] = a;
            }
#pragma unroll
            for (int g = 0; g < 4; ++g) {
                half8 bw = *(const half8*)(wih_p + ((size_t)((g * 8 + ut) * 4 + ks) * 64 + L) * 8);
#pragma unroll
                for (int mt = 0; mt < 3; ++mt)
                    accx[mt][g] = __builtin_amdgcn_mfma_f32_16x16x32_f16(ax[mt], bw, accx[mt][g], 0, 0, 0);
            }
        }
        // store gate-interleaved fp16 Pt rows (predicated to 37 rows)
#pragma unroll
        for (int mt = 0; mt < 3; ++mt)
#pragma unroll
            for (int r = 0; r < 4; ++r) {
                const int sl = mt * 16 + q * 4 + r;
                if (sl < PROWS) {
                    half4 o;
                    o[0] = (_Float16)accx[mt][0][r];
                    o[1] = (_Float16)accx[mt][1][r];
                    o[2] = (_Float16)accx[mt][2][r];
                    o[3] = (_Float16)accx[mt][3][r];
                    *(half4*)&Pt[sl * PSTRIDE + u * 4] = o;
                }
            }
    }

    // register-resident w_hh B-fragments (64 VGPRs, loaded ONCE — the 128-reg
    // budget from waves_per_eu(4,4) is what makes this real this time).
    half8 whf[4][4];    // [gate][ks]
#pragma unroll
    for (int g = 0; g < 4; ++g)
#pragma unroll
        for (int ks = 0; ks < 4; ++ks)
            whf[g][ks] = *(const half8*)(whh_p + ((size_t)((g * 8 + ut) * 4 + ks) * 64 + L) * 8);

    __syncthreads();    // Pt visible to all waves

    // h scatter address components (A-fragment layout for unit u, window m)
    const int ks_h = ut >> 1;
    const int qp   = (ut & 1) * 2 + (ln >> 3);

    float cst[2][4] = {{0.f, 0.f, 0.f, 0.f}, {0.f, 0.f, 0.f, 0.f}};
    float mv = -FLT_MAX;

    // ---- steps 0..5, two independent sub-tiles per barrier interval ----
    for (int st = 0; st < FWn; ++st) {
        if (st > 0) __syncthreads();        // prev step's h scatter visible
#pragma unroll
        for (int sub = 0; sub < 2; ++sub) {
            f32x4 acc[4];                   // [gate] over r
#pragma unroll
            for (int r = 0; r < 4; ++r) {
                half4 pv = *(const half4*)&Pt[(sub * 16 + q * 4 + r + st) * PSTRIDE + u * 4];
                acc[0][r] = (float)pv[0]; acc[1][r] = (float)pv[1];
                acc[2][r] = (float)pv[2]; acc[3][r] = (float)pv[3];
            }
            if (st > 0) {
                const _Float16* hb = hsA[(st + 1) & 1][sub];   // h(st-1)
#pragma unroll
                for (int ks = 0; ks < 4; ++ks) {
                    half8 ah = *(const half8*)(hb + (ks * 64 + L) * 8);
#pragma unroll
                    for (int g = 0; g < 4; ++g)
                        acc[g] = __builtin_amdgcn_mfma_f32_16x16x32_f16(ah, whf[g][ks], acc[g], 0, 0, 0);
                }
            }
            _Float16* buf = hsA[st & 1][sub];
#pragma unroll
            for (int r = 0; r < 4; ++r) {
                // pre-activations already scaled: i',f',o' by log2e; g'' by 2log2e
                float a  = __builtin_amdgcn_exp2f(-acc[0][r]);   // exp(-i)
                float cf = __builtin_amdgcn_exp2f(-acc[1][r]);   // exp(-f)
                float bb = __builtin_amdgcn_exp2f(-acc[2][r]);   // exp(-2g)
                float co = __builtin_amdgcn_exp2f(-acc[3][r]);   // exp(-o)
                float ft  = __builtin_amdgcn_rcpf(1.0f + cf);                    // sig(f)
                float itg = (1.0f - bb) * __builtin_amdgcn_rcpf((1.0f + a) * (1.0f + bb)); // sig(i)*tanh(g)
                float cc  = fmaf(cst[sub][r], ft, itg);
                cst[sub][r] = cc;
                float d  = __builtin_amdgcn_exp2f(-LOG2E2 * cc);                 // exp(-2c)
                float hv = (1.0f - d) * __builtin_amdgcn_rcpf((1.0f + co) * (1.0f + d));   // sig(o)*tanh(c)
                if (st < FWn - 1) {
                    buf[ks_h * 512 + (qp * 16 + q * 4 + r) * 8 + j8] = (_Float16)hv;
                } else {
                    const int w = w0 + sub * 16 + q * 4 + r;
                    mv = fmaxf(mv, (w < Wn) ? hv : -FLT_MAX);
                }
            }
        }
    }

    // ---- reduce max across q; lanes q==0 hold result for unit u ----
    mv = fmaxf(mv, __shfl_xor(mv, 16));
    mv = fmaxf(mv, __shfl_xor(mv, 32));
    if (q == 0)
        partial[(size_t)(b * NTILE + tile) * 128 + u] = mv;
}

// ---------------------------------------------------------------------------
// Kernel 2: feat[b][u] = max over tiles; out[b][c] = feat . fc_w[c] + fc_b[c]
// grid 64, block 128
// ---------------------------------------------------------------------------
__global__ void __launch_bounds__(128)
final_kernel(const float* __restrict__ partial, const float* __restrict__ fc_w,
             const float* __restrict__ fc_b, float* __restrict__ out)
{
    const int b = blockIdx.x;
    const int u = threadIdx.x;
    float m = -FLT_MAX;
#pragma unroll
    for (int tl = 0; tl < NTILE; ++tl)
        m = fmaxf(m, partial[(size_t)(b * NTILE + tl) * 128 + u]);
    float v0 = m * fc_w[u];
    float v1 = m * fc_w[128 + u];
#pragma unroll
    for (int off = 1; off < 64; off <<= 1) {
        v0 += __shfl_xor(v0, off);
        v1 += __shfl_xor(v1, off);
    }
    __shared__ float red[2][2];
    if ((u & 63) == 0) { red[u >> 6][0] = v0; red[u >> 6][1] = v1; }
    __syncthreads();
    if (u == 0) {
        out[b * 2 + 0] = red[0][0] + red[1][0] + fc_b[0];
        out[b * 2 + 1] = red[0][1] + red[1][1] + fc_b[1];
    }
}

// ---------------------------------------------------------------------------
extern "C" void kernel_launch(void* const* d_in, const int* in_sizes, int n_in,
                              void* d_out, int out_size, void* d_ws, size_t ws_size,
                              hipStream_t stream)
{
    const int*   inputs = (const int*)d_in[0];
    // d_in[1] = lengths : unused by the reference
    const float* embed  = (const float*)d_in[2];
    const float* w_ih   = (const float*)d_in[3];
    const float* w_hh   = (const float*)d_in[4];
    const float* b_ih   = (const float*)d_in[5];
    const float* b_hh   = (const float*)d_in[6];
    const float* fc_w   = (const float*)d_in[7];
    const float* fc_b   = (const float*)d_in[8];
    float* out = (float*)d_out;

    // workspace: partial (512 KiB) | wih_p, whh_p (128 KiB each)
    float*    partial = (float*)d_ws;
    _Float16* wih_p   = (_Float16*)(partial + Bn * NTILE * 128);
    _Float16* whh_p   = wih_p + 65536;

    pack_w_kernel<<<dim3(256), 256, 0, stream>>>(w_ih, w_hh, wih_p, whh_p);
    lstm_kernel<<<dim3(Bn * NTILE), 512, 0, stream>>>(inputs, embed, wih_p, whh_p,
                                                      b_ih, b_hh, partial);
    final_kernel<<<dim3(Bn), 128, 0, stream>>>(partial, fc_w, fc_b, out);
}